// Round 2
// baseline (92.109 us; speedup 1.0000x reference)
//
#include <hip/hip_runtime.h>
#include <math.h>

#define B    8
#define C    1024
#define M    8
#define HW   4096
#define EPS  1e-6f
#define GAIN 0.3f

#define NT   4            // hw tiles per batch
#define NC   8            // channel chunks
#define NP   (NT*NC)      // stat partials per batch = 32
#define HWT  (HW/NT)      // 1024 hw per tile
#define CCH  (C/NC)       // 128 channels per chunk
#define TPB  256          // threads per block; each thread: 4 hw via float4

// workspace layout (float offsets)
#define OFF_YZP   0                          // [B][NC][M][HW] = 2,097,152 floats
#define OFF_STATP (OFF_YZP + B*NC*M*HW)      // [B][NP][2]     = 512 floats

// ---------------- K1: partial stats + partial yz = W @ z (per c-chunk) -----
__global__ __launch_bounds__(TPB) void k1_partial(const float* __restrict__ z,
                                                  const float* __restrict__ Wd,
                                                  float* __restrict__ ws) {
    int bid = blockIdx.x;
    int nc  = bid % NC;
    int t   = (bid / NC) % NT;
    int b   = bid / (NC * NT);
    int tid = threadIdx.x;
    int hw  = t * HWT + tid * 4;
    int c0  = nc * CCH;

    float4 ym[M];
#pragma unroll
    for (int m = 0; m < M; ++m) ym[m] = make_float4(0.f, 0.f, 0.f, 0.f);
    float su = 0.f, sq = 0.f;

    const float* zp = z + ((size_t)(b * C + c0)) * HW + hw;
#pragma unroll 2
    for (int ci = 0; ci < CCH; ++ci) {
        float4 v = *reinterpret_cast<const float4*>(zp + (size_t)ci * HW);
        su += (v.x + v.y) + (v.z + v.w);
        sq += v.x * v.x + v.y * v.y + v.z * v.z + v.w * v.w;
        int c = c0 + ci;
#pragma unroll
        for (int m = 0; m < M; ++m) {
            float w = Wd[m * C + c];           // uniform -> s_load
            ym[m].x += w * v.x;
            ym[m].y += w * v.y;
            ym[m].z += w * v.z;
            ym[m].w += w * v.w;
        }
    }

    // write yz partials: [b][nc][m][hw]
    float* yzp = ws + OFF_YZP + ((size_t)(b * NC + nc) * M) * HW + hw;
#pragma unroll
    for (int m = 0; m < M; ++m)
        *reinterpret_cast<float4*>(yzp + (size_t)m * HW) = ym[m];

    // deterministic block tree-reduce of stats
    __shared__ float red[2 * TPB];
    red[tid] = su;
    red[TPB + tid] = sq;
    __syncthreads();
    for (int s = TPB / 2; s > 0; s >>= 1) {
        if (tid < s) {
            red[tid] += red[tid + s];
            red[TPB + tid] += red[TPB + tid + s];
        }
        __syncthreads();
    }
    if (tid == 0) {
        float* st = ws + OFF_STATP + ((size_t)b * NP + t * NC + nc) * 2;
        st[0] = red[0];
        st[1] = red[TPB];
    }
}

// ---- K2: finalize stats (in-block), reduce yz partials, apply output ------
__global__ __launch_bounds__(TPB) void k2_apply(const float* __restrict__ z,
                                                const float* __restrict__ Wd,
                                                const float* __restrict__ ws,
                                                float* __restrict__ out) {
    int bid = blockIdx.x;
    int nc  = bid % NC;
    int t   = (bid / NC) % NT;
    int b   = bid / (NC * NT);
    int tid = threadIdx.x;
    int wv  = tid >> 6;
    int l   = tid & 63;
    int hw  = t * HWT + tid * 4;
    int c0  = nc * CCH;

    __shared__ float sh[2 + M];   // mu, istd, s[0..7]

    // stats: wave 0 reduces the NP=32 partial pairs for batch b
    if (wv == 0) {
        float su = 0.f, sq = 0.f;
        if (l < NP) {
            const float* sp = ws + OFF_STATP + ((size_t)b * NP + l) * 2;
            su = sp[0];
            sq = sp[1];
        }
#pragma unroll
        for (int o = 32; o > 0; o >>= 1) {
            su += __shfl_down(su, o);
            sq += __shfl_down(sq, o);
        }
        if (l == 0) {
            const float invN = 1.0f / (float)(C * HW);
            float mu  = su * invN;
            float var = sq * invN - mu * mu;
            sh[0] = mu;
            sh[1] = 1.0f / sqrtf(var + EPS);
        }
    }
    // s[m]: wave wv handles m = wv and m = wv+4
    {
        float sm0 = 0.f, sm1 = 0.f;
#pragma unroll
        for (int k = 0; k < C / 64; ++k) {
            sm0 += Wd[wv * C + k * 64 + l];
            sm1 += Wd[(wv + 4) * C + k * 64 + l];
        }
#pragma unroll
        for (int o = 32; o > 0; o >>= 1) {
            sm0 += __shfl_down(sm0, o);
            sm1 += __shfl_down(sm1, o);
        }
        if (l == 0) {
            sh[2 + wv]     = sm0;
            sh[2 + wv + 4] = sm1;
        }
    }
    __syncthreads();
    float mu   = sh[0];
    float istd = sh[1];

    // per-thread y[m] for its 4 hw positions: reduce yz partials over nc'
    float4 y[M];
#pragma unroll
    for (int m = 0; m < M; ++m) y[m] = make_float4(0.f, 0.f, 0.f, 0.f);
    const float* yzb = ws + OFF_YZP + (size_t)b * NC * M * HW + hw;
#pragma unroll
    for (int ncp = 0; ncp < NC; ++ncp) {
#pragma unroll
        for (int m = 0; m < M; ++m) {
            float4 v = *reinterpret_cast<const float4*>(yzb + ((size_t)(ncp * M + m)) * HW);
            y[m].x += v.x; y[m].y += v.y; y[m].z += v.z; y[m].w += v.w;
        }
    }
#pragma unroll
    for (int m = 0; m < M; ++m) {
        float off = mu * sh[2 + m];
        y[m].x = istd * (y[m].x - off);
        y[m].y = istd * (y[m].y - off);
        y[m].z = istd * (y[m].z - off);
        y[m].w = istd * (y[m].w - off);
    }

    // apply: out = z + GAIN * W^T y over this block's channel chunk
    const float* zp = z + ((size_t)(b * C + c0)) * HW + hw;
    float* op = out + ((size_t)(b * C + c0)) * HW + hw;
#pragma unroll 2
    for (int ci = 0; ci < CCH; ++ci) {
        float4 v = *reinterpret_cast<const float4*>(zp + (size_t)ci * HW);
        int c = c0 + ci;
        float rx = 0.f, ry = 0.f, rz = 0.f, rw = 0.f;
#pragma unroll
        for (int m = 0; m < M; ++m) {
            float w = Wd[m * C + c];           // uniform -> s_load
            rx += w * y[m].x;
            ry += w * y[m].y;
            rz += w * y[m].z;
            rw += w * y[m].w;
        }
        float4 o;
        o.x = v.x + GAIN * rx;
        o.y = v.y + GAIN * ry;
        o.z = v.z + GAIN * rz;
        o.w = v.w + GAIN * rw;
        *reinterpret_cast<float4*>(op + (size_t)ci * HW) = o;
    }
}

extern "C" void kernel_launch(void* const* d_in, const int* in_sizes, int n_in,
                              void* d_out, int out_size, void* d_ws, size_t ws_size,
                              hipStream_t stream) {
    const float* z  = (const float*)d_in[0];   // (8,1024,64,64) fp32
    const float* Wd = (const float*)d_in[1];   // (8,1024) fp32
    float* out = (float*)d_out;                // (8,1024,64,64) fp32
    float* ws  = (float*)d_ws;                 // needs ~8.4 MB

    dim3 blk(TPB);
    k1_partial<<<dim3(B * NT * NC), blk, 0, stream>>>(z, Wd, ws);
    k2_apply<<<dim3(B * NT * NC), blk, 0, stream>>>(z, Wd, ws, out);
}

// Round 3
// 81.679 us; speedup vs baseline: 1.1277x; 1.1277x over previous
//
#include <hip/hip_runtime.h>
#include <math.h>

#define B    8
#define C    1024
#define M    8
#define HW   4096
#define EPS  1e-6f
#define GAIN 0.3f

#define NT   4            // hw tiles per batch (block covers 1024 hw = 256 thr * float4)
#define NC   16           // channel chunks (CCH = 64)
#define NP   (NT*NC)      // stat partials per batch = 64 (one wave-reduce)
#define HWT  (HW/NT)      // 1024
#define CCH  (C/NC)       // 64
#define TPB  256

// workspace layout (float offsets)
#define OFF_YZP   0                          // [B][NC][M][HW] = 4,194,304 floats
#define OFF_STATP (OFF_YZP + B*NC*M*HW)      // [B][NP][2]     = 1024 floats
#define OFF_Y     (OFF_STATP + B*NP*2)       // [B][M][HW]     = 262,144 floats

// ---------------- K1: partial stats + partial yz = W @ z (per c-chunk) -----
__global__ __launch_bounds__(TPB) void k1_partial(const float* __restrict__ z,
                                                  const float* __restrict__ Wd,
                                                  float* __restrict__ ws) {
    int bid = blockIdx.x;
    int nc  = bid % NC;
    int t   = (bid / NC) % NT;
    int b   = bid / (NC * NT);
    int tid = threadIdx.x;
    int hw  = t * HWT + tid * 4;
    int c0  = nc * CCH;

    float4 ym[M];
#pragma unroll
    for (int m = 0; m < M; ++m) ym[m] = make_float4(0.f, 0.f, 0.f, 0.f);
    float su = 0.f, sq = 0.f;

    const float* zp = z + ((size_t)(b * C + c0)) * HW + hw;
#pragma unroll 2
    for (int ci = 0; ci < CCH; ++ci) {
        float4 v = *reinterpret_cast<const float4*>(zp + (size_t)ci * HW);
        su += (v.x + v.y) + (v.z + v.w);
        sq += v.x * v.x + v.y * v.y + v.z * v.z + v.w * v.w;
        int c = c0 + ci;
#pragma unroll
        for (int m = 0; m < M; ++m) {
            float w = Wd[m * C + c];           // uniform -> s_load
            ym[m].x += w * v.x;
            ym[m].y += w * v.y;
            ym[m].z += w * v.z;
            ym[m].w += w * v.w;
        }
    }

    // write yz partials: [b][nc][m][hw]
    float* yzp = ws + OFF_YZP + ((size_t)(b * NC + nc) * M) * HW + hw;
#pragma unroll
    for (int m = 0; m < M; ++m)
        *reinterpret_cast<float4*>(yzp + (size_t)m * HW) = ym[m];

    // deterministic block tree-reduce of stats
    __shared__ float red[2 * TPB];
    red[tid] = su;
    red[TPB + tid] = sq;
    __syncthreads();
    for (int s = TPB / 2; s > 0; s >>= 1) {
        if (tid < s) {
            red[tid] += red[tid + s];
            red[TPB + tid] += red[TPB + tid + s];
        }
        __syncthreads();
    }
    if (tid == 0) {
        float* st = ws + OFF_STATP + ((size_t)b * NP + t * NC + nc) * 2;
        st[0] = red[0];
        st[1] = red[TPB];
    }
}

// ---- K2: per-(b,m) block — finalize stats in-block, reduce yz -> y --------
// grid = 256 blocks: bid -> b = bid/32, m = (bid%32)/4, hwblk = bid%4
__global__ __launch_bounds__(TPB) void k2_reduce_y(const float* __restrict__ Wd,
                                                   float* __restrict__ ws) {
    int bid   = blockIdx.x;
    int b     = bid >> 5;
    int m     = (bid & 31) >> 2;
    int hwblk = bid & 3;
    int tid   = threadIdx.x;
    int hw    = hwblk * 1024 + tid * 4;

    __shared__ float red[TPB];
    __shared__ float sh[3];   // s_m, mu, istd

    // s[m] = sum_c W[m,c] : block tree-reduce
    {
        float sm = Wd[m * C + tid] + Wd[m * C + tid + 256] +
                   Wd[m * C + tid + 512] + Wd[m * C + tid + 768];
        red[tid] = sm;
        __syncthreads();
        for (int s = TPB / 2; s > 0; s >>= 1) {
            if (tid < s) red[tid] += red[tid + s];
            __syncthreads();
        }
        if (tid == 0) sh[0] = red[0];
    }
    // mu/istd for batch b: wave 0 reduces the NP=64 partial pairs
    if (tid < 64) {
        const float* sp = ws + OFF_STATP + ((size_t)b * NP + tid) * 2;
        float su = sp[0], sq = sp[1];
#pragma unroll
        for (int o = 32; o > 0; o >>= 1) {
            su += __shfl_down(su, o);
            sq += __shfl_down(sq, o);
        }
        if (tid == 0) {
            const float invN = 1.0f / (float)(C * HW);
            float mu  = su * invN;
            float var = sq * invN - mu * mu;
            sh[1] = mu;
            sh[2] = 1.0f / sqrtf(var + EPS);
        }
    }
    __syncthreads();
    float off  = sh[1] * sh[0];   // mu * s_m
    float istd = sh[2];

    // reduce yz chunk-partials for (b, m, hw..hw+3)
    float4 acc = make_float4(0.f, 0.f, 0.f, 0.f);
    const float* p = ws + OFF_YZP + ((size_t)b * NC * M + m) * HW + hw;
#pragma unroll
    for (int ncp = 0; ncp < NC; ++ncp) {
        float4 v = *reinterpret_cast<const float4*>(p + (size_t)ncp * M * HW);
        acc.x += v.x; acc.y += v.y; acc.z += v.z; acc.w += v.w;
    }
    float4 y;
    y.x = istd * (acc.x - off);
    y.y = istd * (acc.y - off);
    y.z = istd * (acc.z - off);
    y.w = istd * (acc.w - off);
    *reinterpret_cast<float4*>(ws + OFF_Y + ((size_t)b * M + m) * HW + hw) = y;
}

// ---------------- K3: out = z + GAIN * W^T y -------------------------------
__global__ __launch_bounds__(TPB) void k3_apply(const float* __restrict__ z,
                                                const float* __restrict__ Wd,
                                                const float* __restrict__ ws,
                                                float* __restrict__ out) {
    int bid = blockIdx.x;
    int nc  = bid % NC;
    int t   = (bid / NC) % NT;
    int b   = bid / (NC * NT);
    int tid = threadIdx.x;
    int hw  = t * HWT + tid * 4;
    int c0  = nc * CCH;

    // y[m] for this thread's 4 hw positions: 32 VGPRs
    float4 y[M];
    const float* yp = ws + OFF_Y + (size_t)b * M * HW + hw;
#pragma unroll
    for (int m = 0; m < M; ++m)
        y[m] = *reinterpret_cast<const float4*>(yp + (size_t)m * HW);

    const float* zp = z + ((size_t)(b * C + c0)) * HW + hw;
    float* op = out + ((size_t)(b * C + c0)) * HW + hw;
#pragma unroll 4
    for (int ci = 0; ci < CCH; ++ci) {
        float4 v = *reinterpret_cast<const float4*>(zp + (size_t)ci * HW);
        int c = c0 + ci;
        float rx = 0.f, ry = 0.f, rz = 0.f, rw = 0.f;
#pragma unroll
        for (int m = 0; m < M; ++m) {
            float w = Wd[m * C + c];           // uniform -> s_load
            rx += w * y[m].x;
            ry += w * y[m].y;
            rz += w * y[m].z;
            rw += w * y[m].w;
        }
        float4 o;
        o.x = v.x + GAIN * rx;
        o.y = v.y + GAIN * ry;
        o.z = v.z + GAIN * rz;
        o.w = v.w + GAIN * rw;
        *reinterpret_cast<float4*>(op + (size_t)ci * HW) = o;
    }
}

extern "C" void kernel_launch(void* const* d_in, const int* in_sizes, int n_in,
                              void* d_out, int out_size, void* d_ws, size_t ws_size,
                              hipStream_t stream) {
    const float* z  = (const float*)d_in[0];   // (8,1024,64,64) fp32
    const float* Wd = (const float*)d_in[1];   // (8,1024) fp32
    float* out = (float*)d_out;                // (8,1024,64,64) fp32
    float* ws  = (float*)d_ws;                 // needs ~17.8 MB

    dim3 blk(TPB);
    k1_partial<<<dim3(B * NT * NC), blk, 0, stream>>>(z, Wd, ws);
    k2_reduce_y<<<dim3(B * M * 4), blk, 0, stream>>>(Wd, ws);
    k3_apply<<<dim3(B * NT * NC), blk, 0, stream>>>(z, Wd, ws, out);
}

// Round 5
// 72.862 us; speedup vs baseline: 1.2642x; 1.1210x over previous
//
#include <hip/hip_runtime.h>
#include <math.h>

#define B    8
#define C    1024
#define M    8
#define HW   4096
#define EPS  1e-6f
#define GAIN 0.3f

#define NT   4            // hw tiles per batch (1024 hw per block = 256 thr * float4)
#define NC   8            // channel chunks (CCH = 128)
#define NP   (NT*NC)      // stat partials per batch = 32
#define HWT  (HW/NT)      // 1024
#define CCH  (C/NC)       // 128
#define TPB  256

typedef float floatx4 __attribute__((ext_vector_type(4)));

// workspace layout (float offsets)
#define OFF_YZP   0                          // [B][NC][M][HW] = 2,097,152 floats
#define OFF_STATP (OFF_YZP + B*NC*M*HW)      // [B][NP][2]     = 512 floats
#define OFF_Y     (OFF_STATP + B*NP*2)       // [B][M][HW]     = 262,144 floats

// ---------------- K1: partial stats + partial yz = W @ z (per c-chunk) -----
// grid 256 = B*NT*NC, one block per CU; z read is the cold HBM pass.
__global__ __launch_bounds__(TPB) void k1_partial(const float* __restrict__ z,
                                                  const float* __restrict__ Wd,
                                                  float* __restrict__ ws) {
    int bid = blockIdx.x;
    int nc  = bid % NC;
    int t   = (bid / NC) % NT;
    int b   = bid / (NC * NT);
    int tid = threadIdx.x;
    int hw  = t * HWT + tid * 4;
    int c0  = nc * CCH;

    float4 ym[M];
#pragma unroll
    for (int m = 0; m < M; ++m) ym[m] = make_float4(0.f, 0.f, 0.f, 0.f);
    float su = 0.f, sq = 0.f;

    const float* zp = z + ((size_t)(b * C + c0)) * HW + hw;
#pragma unroll 4
    for (int ci = 0; ci < CCH; ++ci) {
        float4 v = *reinterpret_cast<const float4*>(zp + (size_t)ci * HW);
        su += (v.x + v.y) + (v.z + v.w);
        sq += v.x * v.x + v.y * v.y + v.z * v.z + v.w * v.w;
        int c = c0 + ci;
#pragma unroll
        for (int m = 0; m < M; ++m) {
            float w = Wd[m * C + c];           // uniform -> s_load
            ym[m].x += w * v.x;
            ym[m].y += w * v.y;
            ym[m].z += w * v.z;
            ym[m].w += w * v.w;
        }
    }

    // write yz partials: [b][nc][m][hw]
    float* yzp = ws + OFF_YZP + ((size_t)(b * NC + nc) * M) * HW + hw;
#pragma unroll
    for (int m = 0; m < M; ++m)
        *reinterpret_cast<float4*>(yzp + (size_t)m * HW) = ym[m];

    // deterministic block tree-reduce of stats
    __shared__ float red[2 * TPB];
    red[tid] = su;
    red[TPB + tid] = sq;
    __syncthreads();
    for (int s = TPB / 2; s > 0; s >>= 1) {
        if (tid < s) {
            red[tid] += red[tid + s];
            red[TPB + tid] += red[TPB + tid + s];
        }
        __syncthreads();
    }
    if (tid == 0) {
        float* st = ws + OFF_STATP + ((size_t)b * NP + t * NC + nc) * 2;
        st[0] = red[0];
        st[1] = red[TPB];
    }
}

// ---- K2: per-(b,m,hwblk) block — finalize stats in two waves, reduce yz -> y
// grid 256: bid -> b = bid/32, m = (bid%32)/4, hwblk = bid%4
__global__ __launch_bounds__(TPB) void k2_reduce_y(const float* __restrict__ Wd,
                                                   float* __restrict__ ws) {
    int bid   = blockIdx.x;
    int b     = bid >> 5;
    int m     = (bid & 31) >> 2;
    int hwblk = bid & 3;
    int tid   = threadIdx.x;
    int wv    = tid >> 6;
    int l     = tid & 63;
    int hw    = hwblk * 1024 + tid * 4;

    __shared__ float sh[3];   // mu, istd, s_m

    if (wv == 0) {
        // stats for batch b: NP=32 partial pairs, lanes 0..31
        float su = 0.f, sq = 0.f;
        if (l < NP) {
            const float* sp = ws + OFF_STATP + ((size_t)b * NP + l) * 2;
            su = sp[0];
            sq = sp[1];
        }
#pragma unroll
        for (int o = 16; o > 0; o >>= 1) {
            su += __shfl_down(su, o);
            sq += __shfl_down(sq, o);
        }
        if (l == 0) {
            const float invN = 1.0f / (float)(C * HW);
            float mu  = su * invN;
            float var = sq * invN - mu * mu;
            sh[0] = mu;
            sh[1] = 1.0f / sqrtf(var + EPS);
        }
    } else if (wv == 1) {
        // s[m] = sum_c W[m,c] : one wave, 16 loads/lane
        float sm = 0.f;
#pragma unroll
        for (int k = 0; k < C / 64; ++k) sm += Wd[m * C + k * 64 + l];
#pragma unroll
        for (int o = 32; o > 0; o >>= 1) sm += __shfl_down(sm, o);
        if (l == 0) sh[2] = sm;
    }
    __syncthreads();
    float mu   = sh[0];
    float istd = sh[1];
    float off  = mu * sh[2];

    // reduce yz chunk-partials for (b, m, hw..hw+3)
    float4 acc = make_float4(0.f, 0.f, 0.f, 0.f);
    const float* p = ws + OFF_YZP + ((size_t)b * NC * M + m) * HW + hw;
#pragma unroll
    for (int ncp = 0; ncp < NC; ++ncp) {
        float4 v = *reinterpret_cast<const float4*>(p + (size_t)ncp * M * HW);
        acc.x += v.x; acc.y += v.y; acc.z += v.z; acc.w += v.w;
    }
    float4 y;
    y.x = istd * (acc.x - off);
    y.y = istd * (acc.y - off);
    y.z = istd * (acc.z - off);
    y.w = istd * (acc.w - off);
    *reinterpret_cast<float4*>(ws + OFF_Y + ((size_t)b * M + m) * HW + hw) = y;
}

// ---------------- K3: out = z + GAIN * W^T y -------------------------------
// z should be L3-resident from K1's pass; out stores are nontemporal so the
// write stream does not evict z from L3 mid-kernel.
__global__ __launch_bounds__(TPB) void k3_apply(const float* __restrict__ z,
                                                const float* __restrict__ Wd,
                                                const float* __restrict__ ws,
                                                float* __restrict__ out) {
    int bid = blockIdx.x;
    int nc  = bid % NC;
    int t   = (bid / NC) % NT;
    int b   = bid / (NC * NT);
    int tid = threadIdx.x;
    int hw  = t * HWT + tid * 4;
    int c0  = nc * CCH;

    // y[m] for this thread's 4 hw positions: 32 VGPRs (heavily reused, L2-hot)
    float4 y[M];
    const float* yp = ws + OFF_Y + (size_t)b * M * HW + hw;
#pragma unroll
    for (int m = 0; m < M; ++m)
        y[m] = *reinterpret_cast<const float4*>(yp + (size_t)m * HW);

    const float* zp = z + ((size_t)(b * C + c0)) * HW + hw;
    float* op = out + ((size_t)(b * C + c0)) * HW + hw;
#pragma unroll 4
    for (int ci = 0; ci < CCH; ++ci) {
        float4 v = *reinterpret_cast<const float4*>(zp + (size_t)ci * HW);
        int c = c0 + ci;
        float rx = 0.f, ry = 0.f, rz = 0.f, rw = 0.f;
#pragma unroll
        for (int m = 0; m < M; ++m) {
            float w = Wd[m * C + c];           // uniform -> s_load
            rx += w * y[m].x;
            ry += w * y[m].y;
            rz += w * y[m].z;
            rw += w * y[m].w;
        }
        floatx4 o;
        o.x = v.x + GAIN * rx;
        o.y = v.y + GAIN * ry;
        o.z = v.z + GAIN * rz;
        o.w = v.w + GAIN * rw;
        __builtin_nontemporal_store(o, reinterpret_cast<floatx4*>(op + (size_t)ci * HW));
    }
}

extern "C" void kernel_launch(void* const* d_in, const int* in_sizes, int n_in,
                              void* d_out, int out_size, void* d_ws, size_t ws_size,
                              hipStream_t stream) {
    const float* z  = (const float*)d_in[0];   // (8,1024,64,64) fp32
    const float* Wd = (const float*)d_in[1];   // (8,1024) fp32
    float* out = (float*)d_out;                // (8,1024,64,64) fp32
    float* ws  = (float*)d_ws;                 // needs ~9.4 MB

    dim3 blk(TPB);
    k1_partial<<<dim3(B * NT * NC), blk, 0, stream>>>(z, Wd, ws);
    k2_reduce_y<<<dim3(B * M * 4), blk, 0, stream>>>(Wd, ws);
    k3_apply<<<dim3(B * NT * NC), blk, 0, stream>>>(z, Wd, ws, out);
}